// Round 1
// baseline (837.025 us; speedup 1.0000x reference)
//
#include <hip/hip_runtime.h>
#include <hip/hip_bf16.h>

// ---------------------------------------------------------------------------
// Generic 3x3 VALID conv, stride 1. Block = 16x16 spatial tile, grid.z = oc.
// Stages the (16+2)^2 input tile for all Cin channels + the oc's weights in LDS.
// ---------------------------------------------------------------------------
__global__ void conv3x3_kernel(const float* __restrict__ src, int Cin, int H, int W,
                               const float* __restrict__ w, const float* __restrict__ b,
                               float* __restrict__ dst, int OH, int OW) {
    extern __shared__ float lds[];           // [Cin][18*18] + [Cin*9]
    float* xs = lds;
    float* ws = lds + Cin * 324;
    const int oc  = blockIdx.z;
    const int tx0 = blockIdx.x * 16, ty0 = blockIdx.y * 16;
    const int tid = threadIdx.y * 16 + threadIdx.x;

    for (int i = tid; i < Cin * 9; i += 256) ws[i] = w[oc * Cin * 9 + i];
    for (int i = tid; i < Cin * 324; i += 256) {
        int ic = i / 324;
        int r  = (i % 324) / 18;
        int cc = (i % 324) % 18;
        int y = ty0 + r, x = tx0 + cc;
        xs[i] = (y < H && x < W) ? src[((size_t)ic * H + y) * W + x] : 0.f;
    }
    __syncthreads();

    const int ox = tx0 + threadIdx.x, oy = ty0 + threadIdx.y;
    if (ox >= OW || oy >= OH) return;
    float acc = b[oc];
    for (int ic = 0; ic < Cin; ++ic) {
        const float* xp = &xs[ic * 324 + threadIdx.y * 18 + threadIdx.x];
        const float* wp = &ws[ic * 9];
        #pragma unroll
        for (int kh = 0; kh < 3; ++kh)
            #pragma unroll
            for (int kw = 0; kw < 3; ++kw)
                acc += xp[kh * 18 + kw] * wp[kh * 3 + kw];
    }
    dst[((size_t)oc * OH + oy) * OW + ox] = acc;
}

// ---------------------------------------------------------------------------
// Batch-norm statistics (training mode, biased variance). One block / channel.
// Writes [c] -> (inv = g/sqrt(var+eps), shift = b - mean*inv).
// ---------------------------------------------------------------------------
__global__ void bn_stats_kernel(const float* __restrict__ src, int spatial,
                                const float* __restrict__ g, const float* __restrict__ bb,
                                float* __restrict__ inv_shift) {
    const int c = blockIdx.x;
    const float* p = src + (size_t)c * spatial;
    float s = 0.f, sq = 0.f;
    for (int i = threadIdx.x; i < spatial; i += blockDim.x) {
        float x = p[i];
        s += x; sq += x * x;
    }
    __shared__ float rs[256], rq[256];
    rs[threadIdx.x] = s; rq[threadIdx.x] = sq;
    __syncthreads();
    for (int off = 128; off > 0; off >>= 1) {
        if (threadIdx.x < off) {
            rs[threadIdx.x] += rs[threadIdx.x + off];
            rq[threadIdx.x] += rq[threadIdx.x + off];
        }
        __syncthreads();
    }
    if (threadIdx.x == 0) {
        float m   = rs[0] / (float)spatial;
        float var = rq[0] / (float)spatial - m * m;
        float inv = g[c] * rsqrtf(var + 1e-5f);
        inv_shift[c * 2]     = inv;
        inv_shift[c * 2 + 1] = bb[c] - m * inv;
    }
}

// ---------------------------------------------------------------------------
// Fused BN-apply + ReLU + 2x2/2 max-pool (VALID).
// ---------------------------------------------------------------------------
__global__ void bn_pool_kernel(const float* __restrict__ src,
                               const float* __restrict__ inv_shift,
                               int H, int W, int OH, int OW, int C,
                               float* __restrict__ dst) {
    int i = blockIdx.x * blockDim.x + threadIdx.x;
    if (i >= C * OH * OW) return;
    int ox = i % OW;
    int oy = (i / OW) % OH;
    int c  = i / (OW * OH);
    float inv = inv_shift[c * 2], sh = inv_shift[c * 2 + 1];
    const float* p = src + ((size_t)c * H + 2 * oy) * W + 2 * ox;
    float a = fmaxf(fmaf(p[0],     inv, sh), 0.f);
    float b = fmaxf(fmaf(p[1],     inv, sh), 0.f);
    float d = fmaxf(fmaf(p[W],     inv, sh), 0.f);
    float e = fmaxf(fmaf(p[W + 1], inv, sh), 0.f);
    dst[i] = fmaxf(fmaxf(a, b), fmaxf(d, e));
}

// ---------------------------------------------------------------------------
// 1x1-conv QKV projection. grid.x covers N (256/block), grid.y = oc-group of 8.
// oc < Cqk -> q, oc < 2*Cqk -> k, else -> v. Weights staged in LDS.
// ---------------------------------------------------------------------------
__global__ void qkv_proj_kernel(const float* __restrict__ xf, int N, int C, int Cqk,
                                const float* __restrict__ qw, const float* __restrict__ qb,
                                const float* __restrict__ kw, const float* __restrict__ kb,
                                const float* __restrict__ vw, const float* __restrict__ vb,
                                float* __restrict__ q, float* __restrict__ k,
                                float* __restrict__ v) {
    constexpr int OCG = 8;
    __shared__ float wl[OCG * 64 + OCG];
    const int g0 = blockIdx.y * OCG;
    const int tid = threadIdx.x;
    for (int i = tid; i < OCG * C; i += blockDim.x) {
        int o = i / C, cc = i % C;
        int oc = g0 + o;
        const float* wsrc = (oc < Cqk) ? (qw + oc * C)
                          : (oc < 2 * Cqk) ? (kw + (oc - Cqk) * C)
                          : (vw + (oc - 2 * Cqk) * C);
        wl[o * C + cc] = wsrc[cc];
    }
    if (tid < OCG) {
        int oc = g0 + tid;
        wl[OCG * C + tid] = (oc < Cqk) ? qb[oc]
                          : (oc < 2 * Cqk) ? kb[oc - Cqk]
                          : vb[oc - 2 * Cqk];
    }
    __syncthreads();
    int n = blockIdx.x * blockDim.x + tid;
    if (n >= N) return;
    float acc[OCG];
    #pragma unroll
    for (int o = 0; o < OCG; ++o) acc[o] = wl[OCG * C + o];
    for (int c = 0; c < C; ++c) {
        float xv = xf[(size_t)c * N + n];
        #pragma unroll
        for (int o = 0; o < OCG; ++o) acc[o] += xv * wl[o * C + c];
    }
    #pragma unroll
    for (int o = 0; o < OCG; ++o) {
        int oc = g0 + o;
        float* dstp = (oc < Cqk) ? (q + (size_t)oc * N)
                    : (oc < 2 * Cqk) ? (k + (size_t)(oc - Cqk) * N)
                    : (v + (size_t)(oc - 2 * Cqk) * N);
        dstp[n] = acc[o];
    }
}

// ---------------------------------------------------------------------------
// Flash-style attention, key-split partials. One thread = one query.
// grid.x = query blocks (256/block), grid.y = key split s.
// Energies are O(1) -> exact zero-shift softmax (no overflow possible here),
// so key-split partials combine exactly: out = sum(acc)/sum(l).
// K/V tiles staged in LDS row-major [mm][CQK+CV], padded; reads are broadcast.
// ---------------------------------------------------------------------------
template <int CQK, int CV, int ROWP>
__global__ void flash_kernel(const float* __restrict__ q, const float* __restrict__ k,
                             const float* __restrict__ v, int N, int chunk,
                             float* __restrict__ l_part, float* __restrict__ acc_part) {
    constexpr int TK = 64;
    __shared__ float tile[TK * ROWP];
    const int n  = blockIdx.x * blockDim.x + threadIdx.x;
    const int s  = blockIdx.y;
    const int m0 = s * chunk;
    const int m1 = min(N, m0 + chunk);
    const bool active = (n < N);

    float qr[CQK];
    if (active) {
        #pragma unroll
        for (int c = 0; c < CQK; ++c) qr[c] = q[(size_t)c * N + n];
    }
    float acc[CV];
    #pragma unroll
    for (int i = 0; i < CV; ++i) acc[i] = 0.f;
    float l = 0.f;

    for (int mt = m0; mt < m1; mt += TK) {
        const int tk = min(TK, m1 - mt);
        __syncthreads();   // protect previous tile
        for (int idx = threadIdx.x; idx < (CQK + CV) * TK; idx += blockDim.x) {
            int mm = idx % TK;
            int c  = idx / TK;
            float val = 0.f;
            if (mm < tk)
                val = (c < CQK) ? k[(size_t)c * N + mt + mm]
                                : v[(size_t)(c - CQK) * N + mt + mm];
            tile[mm * ROWP + c] = val;
        }
        __syncthreads();
        if (active) {
            for (int mm = 0; mm < tk; ++mm) {
                const float* row = &tile[mm * ROWP];
                float e = 0.f;
                #pragma unroll
                for (int c = 0; c < CQK; ++c) e += qr[c] * row[c];
                float p = __expf(e);
                l += p;
                #pragma unroll
                for (int cv = 0; cv < CV; ++cv) acc[cv] += p * row[CQK + cv];
            }
        }
    }
    if (active) {
        l_part[(size_t)s * N + n] = l;
        for (int cv = 0; cv < CV; ++cv)
            acc_part[((size_t)s * CV + cv) * N + n] = acc[cv];
    }
}

// ---------------------------------------------------------------------------
// Combine key-split partials + gamma * out + residual.
// ---------------------------------------------------------------------------
__global__ void combine_kernel(const float* __restrict__ acc_part,
                               const float* __restrict__ l_part,
                               int nsplit, int N, int CV,
                               const float* __restrict__ gamma,
                               const float* __restrict__ x_res,
                               float* __restrict__ out) {
    int i = blockIdx.x * blockDim.x + threadIdx.x;
    if (i >= CV * N) return;
    int n  = i % N;
    int cv = i / N;
    float l = 0.f, a = 0.f;
    for (int s = 0; s < nsplit; ++s) l += l_part[(size_t)s * N + n];
    for (int s = 0; s < nsplit; ++s) a += acc_part[((size_t)s * CV + cv) * N + n];
    out[i] = gamma[0] * (a / l) + x_res[i];
}

// ---------------------------------------------------------------------------
// FC: out[50] = h @ W^T + b.  Two stage: per-(row,chunk) partial then reduce.
// ---------------------------------------------------------------------------
__global__ void fc_partial_kernel(const float* __restrict__ h, const float* __restrict__ w,
                                  int K, int nchunk, float* __restrict__ partial) {
    const int r = blockIdx.y, cb = blockIdx.x;
    const int chunk = K / nchunk;          // K divisible by nchunk (and by 4)
    const int j0 = cb * chunk;
    const int j1 = (cb == nchunk - 1) ? K : j0 + chunk;
    const float* wr = w + (size_t)r * K;
    float s = 0.f;
    for (int j = j0 + threadIdx.x * 4; j + 3 < j1; j += blockDim.x * 4) {
        float4 hv = *reinterpret_cast<const float4*>(h + j);
        float4 wv = *reinterpret_cast<const float4*>(wr + j);
        s += hv.x * wv.x + hv.y * wv.y + hv.z * wv.z + hv.w * wv.w;
    }
    __shared__ float red[256];
    red[threadIdx.x] = s;
    __syncthreads();
    for (int off = 128; off > 0; off >>= 1) {
        if (threadIdx.x < off) red[threadIdx.x] += red[threadIdx.x + off];
        __syncthreads();
    }
    if (threadIdx.x == 0) partial[r * gridDim.x + cb] = red[0];
}

__global__ void fc_final_kernel(const float* __restrict__ partial,
                                const float* __restrict__ b, int nchunk,
                                float* __restrict__ out) {
    int r = threadIdx.x;
    if (r < 50) {
        float s = b[r];
        for (int i = 0; i < nchunk; ++i) s += partial[r * nchunk + i];
        out[r] = s;
    }
}

// ---------------------------------------------------------------------------
extern "C" void kernel_launch(void* const* d_in, const int* in_sizes, int n_in,
                              void* d_out, int out_size, void* d_ws, size_t ws_size,
                              hipStream_t stream) {
    const float* x    = (const float*)d_in[0];
    const float* c1w  = (const float*)d_in[1];
    const float* c1b  = (const float*)d_in[2];
    const float* bn1g = (const float*)d_in[3];
    const float* bn1b = (const float*)d_in[4];
    const float* a1qw = (const float*)d_in[5];
    const float* a1qb = (const float*)d_in[6];
    const float* a1kw = (const float*)d_in[7];
    const float* a1kb = (const float*)d_in[8];
    const float* a1vw = (const float*)d_in[9];
    const float* a1vb = (const float*)d_in[10];
    const float* a1g  = (const float*)d_in[11];
    const float* c2w  = (const float*)d_in[12];
    const float* c2b  = (const float*)d_in[13];
    const float* bn2g = (const float*)d_in[14];
    const float* bn2b = (const float*)d_in[15];
    const float* a2qw = (const float*)d_in[16];
    const float* a2qb = (const float*)d_in[17];
    const float* a2kw = (const float*)d_in[18];
    const float* a2kb = (const float*)d_in[19];
    const float* a2vw = (const float*)d_in[20];
    const float* a2vb = (const float*)d_in[21];
    const float* a2g  = (const float*)d_in[22];
    const float* fcw  = (const float*)d_in[23];
    const float* fcb  = (const float*)d_in[24];
    float* out = (float*)d_out;

    const int N1 = 127 * 127;   // 16129
    const int N2 = 62 * 62;     // 3844
    const int NS1 = 8, NS2 = 16;

    size_t off = 0;
    auto alloc = [&](size_t n) {
        float* p = (float*)d_ws + off;
        off += (n + 15) & ~(size_t)15;
        return p;
    };
    float* h1  = alloc((size_t)32 * 254 * 254);
    float* bnA = alloc(64);
    float* p1  = alloc((size_t)32 * N1);
    float* q1  = alloc((size_t)4 * N1);
    float* k1  = alloc((size_t)4 * N1);
    float* v1  = alloc((size_t)32 * N1);
    float* l1  = alloc((size_t)NS1 * N1);
    float* a1p = alloc((size_t)NS1 * 32 * N1);
    float* ao1 = alloc((size_t)32 * N1);
    float* h2  = alloc((size_t)64 * 125 * 125);
    float* bnB = alloc(128);
    float* p2  = alloc((size_t)64 * N2);
    float* q2  = alloc((size_t)8 * N2);
    float* k2  = alloc((size_t)8 * N2);
    float* v2  = alloc((size_t)64 * N2);
    float* l2  = alloc((size_t)NS2 * N2);
    float* a2p = alloc((size_t)NS2 * 64 * N2);
    float* ao2 = alloc((size_t)64 * N2);
    float* fcp = alloc(512);

    // ---- stage 1: conv1 [3,256,256] -> [32,254,254]
    {
        size_t smem = (3 * 324 + 3 * 9) * sizeof(float);
        conv3x3_kernel<<<dim3(16, 16, 32), dim3(16, 16), smem, stream>>>(
            x, 3, 256, 256, c1w, c1b, h1, 254, 254);
    }
    bn_stats_kernel<<<32, 256, 0, stream>>>(h1, 254 * 254, bn1g, bn1b, bnA);
    bn_pool_kernel<<<(32 * N1 + 255) / 256, 256, 0, stream>>>(
        h1, bnA, 254, 254, 127, 127, 32, p1);

    // ---- attention 1 (C=32, Cqk=4, N=16129)
    qkv_proj_kernel<<<dim3((N1 + 255) / 256, 5), 256, 0, stream>>>(
        p1, N1, 32, 4, a1qw, a1qb, a1kw, a1kb, a1vw, a1vb, q1, k1, v1);
    {
        int chunk = (N1 + NS1 - 1) / NS1;   // 2017
        flash_kernel<4, 32, 40><<<dim3((N1 + 255) / 256, NS1), 256, 0, stream>>>(
            q1, k1, v1, N1, chunk, l1, a1p);
    }
    combine_kernel<<<(32 * N1 + 255) / 256, 256, 0, stream>>>(
        a1p, l1, NS1, N1, 32, a1g, p1, ao1);

    // ---- stage 2: conv2 [32,127,127] -> [64,125,125]
    {
        size_t smem = (32 * 324 + 32 * 9) * sizeof(float);
        conv3x3_kernel<<<dim3(8, 8, 64), dim3(16, 16), smem, stream>>>(
            ao1, 32, 127, 127, c2w, c2b, h2, 125, 125);
    }
    bn_stats_kernel<<<64, 256, 0, stream>>>(h2, 125 * 125, bn2g, bn2b, bnB);
    bn_pool_kernel<<<(64 * N2 + 255) / 256, 256, 0, stream>>>(
        h2, bnB, 125, 125, 62, 62, 64, p2);

    // ---- attention 2 (C=64, Cqk=8, N=3844)
    qkv_proj_kernel<<<dim3((N2 + 255) / 256, 10), 256, 0, stream>>>(
        p2, N2, 64, 8, a2qw, a2qb, a2kw, a2kb, a2vw, a2vb, q2, k2, v2);
    {
        int chunk = (N2 + NS2 - 1) / NS2;   // 241
        flash_kernel<8, 64, 80><<<dim3((N2 + 255) / 256, NS2), 256, 0, stream>>>(
            q2, k2, v2, N2, chunk, l2, a2p);
    }
    combine_kernel<<<(64 * N2 + 255) / 256, 256, 0, stream>>>(
        a2p, l2, NS2, N2, 64, a2g, p2, ao2);

    // ---- FC [246016] -> [50]
    fc_partial_kernel<<<dim3(8, 50), 256, 0, stream>>>(ao2, fcw, 64 * N2, 8, fcp);
    fc_final_kernel<<<1, 64, 0, stream>>>(fcp, fcb, 8, out);
}

// Round 2
// 275.755 us; speedup vs baseline: 3.0354x; 3.0354x over previous
//
#include <hip/hip_runtime.h>
#include <hip/hip_bf16.h>

typedef float f32x4 __attribute__((ext_vector_type(4)));
typedef short bf16x8 __attribute__((ext_vector_type(8)));

__device__ inline unsigned short f2bf(float x) {
    __hip_bfloat16 h = __float2bfloat16(x);
    return *reinterpret_cast<unsigned short*>(&h);
}

// ---------------------------------------------------------------------------
// Generic 3x3 VALID conv, stride 1. Block = 16x16 spatial tile, grid.z = oc.
// ---------------------------------------------------------------------------
__global__ void conv3x3_kernel(const float* __restrict__ src, int Cin, int H, int W,
                               const float* __restrict__ w, const float* __restrict__ b,
                               float* __restrict__ dst, int OH, int OW) {
    extern __shared__ float lds[];           // [Cin][18*18] + [Cin*9]
    float* xs = lds;
    float* ws = lds + Cin * 324;
    const int oc  = blockIdx.z;
    const int tx0 = blockIdx.x * 16, ty0 = blockIdx.y * 16;
    const int tid = threadIdx.y * 16 + threadIdx.x;

    for (int i = tid; i < Cin * 9; i += 256) ws[i] = w[oc * Cin * 9 + i];
    for (int i = tid; i < Cin * 324; i += 256) {
        int ic = i / 324;
        int r  = (i % 324) / 18;
        int cc = (i % 324) % 18;
        int y = ty0 + r, x = tx0 + cc;
        xs[i] = (y < H && x < W) ? src[((size_t)ic * H + y) * W + x] : 0.f;
    }
    __syncthreads();

    const int ox = tx0 + threadIdx.x, oy = ty0 + threadIdx.y;
    if (ox >= OW || oy >= OH) return;
    float acc = b[oc];
    for (int ic = 0; ic < Cin; ++ic) {
        const float* xp = &xs[ic * 324 + threadIdx.y * 18 + threadIdx.x];
        const float* wp = &ws[ic * 9];
        #pragma unroll
        for (int kh = 0; kh < 3; ++kh)
            #pragma unroll
            for (int kw = 0; kw < 3; ++kw)
                acc += xp[kh * 18 + kw] * wp[kh * 3 + kw];
    }
    dst[((size_t)oc * OH + oy) * OW + ox] = acc;
}

// ---------------------------------------------------------------------------
// BN statistics, two-pass: per-(channel, slice) partials, then finalize.
// ---------------------------------------------------------------------------
__global__ void bn_part_kernel(const float* __restrict__ src, int spatial,
                               float* __restrict__ part) {
    const int c = blockIdx.x, sb = blockIdx.y, SB = gridDim.y;
    const float* p = src + (size_t)c * spatial;
    const int nv4 = spatial >> 2;
    const int per = (nv4 + SB - 1) / SB;
    const int j0 = sb * per, j1 = min(nv4, j0 + per);
    float s = 0.f, sq = 0.f;
    const float4* p4 = (const float4*)p;
    for (int j = j0 + (int)threadIdx.x; j < j1; j += 256) {
        float4 x = p4[j];
        s  += x.x + x.y + x.z + x.w;
        sq += x.x * x.x + x.y * x.y + x.z * x.z + x.w * x.w;
    }
    if (sb == 0) {
        for (int j = (nv4 << 2) + (int)threadIdx.x; j < spatial; j += 256) {
            float x = p[j]; s += x; sq += x * x;
        }
    }
    __shared__ float rs[256], rq[256];
    rs[threadIdx.x] = s; rq[threadIdx.x] = sq;
    __syncthreads();
    for (int off = 128; off > 0; off >>= 1) {
        if ((int)threadIdx.x < off) {
            rs[threadIdx.x] += rs[threadIdx.x + off];
            rq[threadIdx.x] += rq[threadIdx.x + off];
        }
        __syncthreads();
    }
    if (threadIdx.x == 0) {
        part[(c * SB + sb) * 2]     = rs[0];
        part[(c * SB + sb) * 2 + 1] = rq[0];
    }
}

__global__ void bn_final_kernel(const float* __restrict__ part, int SB, int spatial,
                                const float* __restrict__ g, const float* __restrict__ bb,
                                float* __restrict__ inv_shift) {
    int c = blockIdx.x;
    if (threadIdx.x != 0) return;
    float s = 0.f, sq = 0.f;
    for (int i = 0; i < SB; ++i) {
        s  += part[(c * SB + i) * 2];
        sq += part[(c * SB + i) * 2 + 1];
    }
    float m   = s / (float)spatial;
    float var = sq / (float)spatial - m * m;
    float inv = g[c] * rsqrtf(var + 1e-5f);
    inv_shift[c * 2]     = inv;
    inv_shift[c * 2 + 1] = bb[c] - m * inv;
}

// ---------------------------------------------------------------------------
// Fused BN-apply + ReLU + 2x2/2 max-pool (VALID).
// ---------------------------------------------------------------------------
__global__ void bn_pool_kernel(const float* __restrict__ src,
                               const float* __restrict__ inv_shift,
                               int H, int W, int OH, int OW, int C,
                               float* __restrict__ dst) {
    int i = blockIdx.x * blockDim.x + threadIdx.x;
    if (i >= C * OH * OW) return;
    int ox = i % OW;
    int oy = (i / OW) % OH;
    int c  = i / (OW * OH);
    float inv = inv_shift[c * 2], sh = inv_shift[c * 2 + 1];
    const float* p = src + ((size_t)c * H + 2 * oy) * W + 2 * ox;
    float a = fmaxf(fmaf(p[0],     inv, sh), 0.f);
    float b = fmaxf(fmaf(p[1],     inv, sh), 0.f);
    float d = fmaxf(fmaf(p[W],     inv, sh), 0.f);
    float e = fmaxf(fmaf(p[W + 1], inv, sh), 0.f);
    dst[i] = fmaxf(fmaxf(a, b), fmaxf(d, e));
}

// ---------------------------------------------------------------------------
// 1x1-conv QKV projection. q,k fp32 (stride NP); v bf16 (stride NP).
// ---------------------------------------------------------------------------
__global__ void qkv_proj_kernel(const float* __restrict__ xf, int N, int NP, int C, int Cqk,
                                const float* __restrict__ qw, const float* __restrict__ qb,
                                const float* __restrict__ kw, const float* __restrict__ kb,
                                const float* __restrict__ vw, const float* __restrict__ vb,
                                float* __restrict__ q, float* __restrict__ k,
                                unsigned short* __restrict__ v) {
    constexpr int OCG = 8;
    __shared__ float wl[OCG * 64 + OCG];
    const int g0 = blockIdx.y * OCG;
    const int tid = threadIdx.x;
    for (int i = tid; i < OCG * C; i += blockDim.x) {
        int o = i / C, cc = i % C;
        int oc = g0 + o;
        const float* wsrc = (oc < Cqk) ? (qw + oc * C)
                          : (oc < 2 * Cqk) ? (kw + (oc - Cqk) * C)
                          : (vw + (oc - 2 * Cqk) * C);
        wl[o * C + cc] = wsrc[cc];
    }
    if (tid < OCG) {
        int oc = g0 + tid;
        wl[OCG * C + tid] = (oc < Cqk) ? qb[oc]
                          : (oc < 2 * Cqk) ? kb[oc - Cqk]
                          : vb[oc - 2 * Cqk];
    }
    __syncthreads();
    int n = blockIdx.x * blockDim.x + tid;
    if (n >= N) return;
    float acc[OCG];
    #pragma unroll
    for (int o = 0; o < OCG; ++o) acc[o] = wl[OCG * C + o];
    for (int c = 0; c < C; ++c) {
        float xv = xf[(size_t)c * N + n];
        #pragma unroll
        for (int o = 0; o < OCG; ++o) acc[o] += xv * wl[o * C + c];
    }
    #pragma unroll
    for (int o = 0; o < OCG; ++o) {
        int oc = g0 + o;
        if (oc < Cqk)            q[(size_t)oc * NP + n] = acc[o];
        else if (oc < 2 * Cqk)   k[(size_t)(oc - Cqk) * NP + n] = acc[o];
        else                     v[(size_t)(oc - 2 * Cqk) * NP + n] = f2bf(acc[o]);
    }
}

// ---------------------------------------------------------------------------
// MFMA flash attention. Block = 4 waves x 16 queries = 64 queries.
// grid.x = ceil(N/64), grid.y = key-splits. Per 32-key chunk:
//   - stage K fp32 [CQK][32] + V bf16 [CV][32] in LDS
//   - each lane computes E/P for (query = lane&15, keys = 8*(lane>>4)+j)
//     which IS the A-fragment layout of mfma_f32_16x16x32_bf16 -> no shuffles
//   - PV via MFMA, acc in fp32 D-frags (col=lane&15=ch, row=4g+reg=query)
// l (softmax denom) reduced with shfl_xor; division happens in combine.
// Outputs: l_part[s][n], acc_part[s][n][cv]  (coalesced D-frag stores).
// ---------------------------------------------------------------------------
template <int CQK, int CV>
__launch_bounds__(256)
__global__ void flash_mfma_kernel(const float* __restrict__ q,
                                  const float* __restrict__ k,
                                  const unsigned short* __restrict__ v,
                                  int N, int NP, int chunk,
                                  float* __restrict__ l_part,
                                  float* __restrict__ acc_part) {
    __shared__ float ksm[CQK * 32];
    __shared__ unsigned short vsm[CV * 32];
    const int tid  = threadIdx.x;
    const int wave = tid >> 6;
    const int lane = tid & 63;
    const int row  = lane & 15;     // query row within wave tile / D column (ch)
    const int g    = lane >> 4;     // k-group
    const int s    = blockIdx.y;
    const int m0   = s * chunk;
    const int m1   = min(N, m0 + chunk);
    const int qb   = blockIdx.x * 64 + wave * 16;
    const int n    = qb + row;      // this lane's query

    float qr[CQK];
    #pragma unroll
    for (int c = 0; c < CQK; ++c)
        qr[c] = (n < N) ? q[(size_t)c * NP + n] : 0.f;

    f32x4 acc[CV / 16];
    #pragma unroll
    for (int f = 0; f < CV / 16; ++f) acc[f] = (f32x4){0.f, 0.f, 0.f, 0.f};
    float lsum = 0.f;

    for (int mt = m0; mt < m1; mt += 32) {
        __syncthreads();
        // stage K
        for (int i = tid; i < CQK * 32; i += 256) {
            int c = i >> 5, kk = i & 31;
            int key = mt + kk;
            ksm[i] = (key < m1) ? k[(size_t)c * NP + key] : 0.f;
        }
        // stage V
        if (mt + 32 <= m1) {
            for (int i = tid * 4; i < CV * 32; i += 1024) {
                int ch = i >> 5, kk = i & 31;
                *(ushort4*)&vsm[i] = *(const ushort4*)&v[(size_t)ch * NP + mt + kk];
            }
        } else {
            for (int i = tid; i < CV * 32; i += 256) {
                int ch = i >> 5, kk = i & 31;
                int key = mt + kk;
                vsm[i] = (key < m1) ? v[(size_t)ch * NP + key] : (unsigned short)0;
            }
        }
        __syncthreads();

        // energies: query n, keys mt+8g .. mt+8g+7
        float e[8];
        #pragma unroll
        for (int j = 0; j < 8; ++j) e[j] = 0.f;
        #pragma unroll
        for (int c = 0; c < CQK; ++c) {
            const float* kp = &ksm[c * 32 + 8 * g];
            #pragma unroll
            for (int j = 0; j < 8; ++j)
                e[j] = fmaf(qr[c], kp[j], e[j]);
        }
        bf16x8 pfrag;
        if (mt + 32 <= m1) {
            #pragma unroll
            for (int j = 0; j < 8; ++j) {
                float p = __expf(e[j]);
                lsum += p;
                pfrag[j] = (short)f2bf(p);
            }
        } else {
            #pragma unroll
            for (int j = 0; j < 8; ++j) {
                float p = (mt + 8 * g + j < m1) ? __expf(e[j]) : 0.f;
                lsum += p;
                pfrag[j] = (short)f2bf(p);
            }
        }
        #pragma unroll
        for (int f = 0; f < CV / 16; ++f) {
            bf16x8 vfrag = *(const bf16x8*)&vsm[(f * 16 + row) * 32 + 8 * g];
            acc[f] = __builtin_amdgcn_mfma_f32_16x16x32_bf16(pfrag, vfrag, acc[f], 0, 0, 0);
        }
    }

    // full softmax denominator for query n: sum over the 4 k-groups
    lsum += __shfl_xor(lsum, 16, 64);
    lsum += __shfl_xor(lsum, 32, 64);
    if (g == 0 && n < N) l_part[(size_t)s * N + n] = lsum;

    // D-frag: channel = row(lane&15), queries qb + 4g + r2
    #pragma unroll
    for (int f = 0; f < CV / 16; ++f) {
        #pragma unroll
        for (int r2 = 0; r2 < 4; ++r2) {
            int nq = qb + 4 * g + r2;
            if (nq < N)
                acc_part[((size_t)s * N + nq) * CV + f * 16 + row] = acc[f][r2];
        }
    }
}

// ---------------------------------------------------------------------------
// Combine key-split partials: out[cv][n] = gamma * (sum_s acc[s][n][cv]) /
//                                          (sum_s l[s][n]) + x_res[cv][n]
// ---------------------------------------------------------------------------
__global__ void combine_kernel(const float* __restrict__ acc_part,
                               const float* __restrict__ l_part,
                               int nsplit, int N, int CV,
                               const float* __restrict__ gamma,
                               const float* __restrict__ x_res,
                               float* __restrict__ out) {
    int i = blockIdx.x * blockDim.x + threadIdx.x;
    if (i >= CV * N) return;
    int cv = i % CV;
    int n  = i / CV;
    float l = 0.f, a = 0.f;
    for (int s = 0; s < nsplit; ++s) l += l_part[(size_t)s * N + n];
    for (int s = 0; s < nsplit; ++s) a += acc_part[((size_t)s * N + n) * CV + cv];
    out[(size_t)cv * N + n] = gamma[0] * (a / l) + x_res[(size_t)cv * N + n];
}

// ---------------------------------------------------------------------------
// FC: out[50] = h @ W^T + b.
// ---------------------------------------------------------------------------
__global__ void fc_partial_kernel(const float* __restrict__ h, const float* __restrict__ w,
                                  int K, int nchunk, float* __restrict__ partial) {
    const int r = blockIdx.y, cb = blockIdx.x;
    const int chunk = K / nchunk;
    const int j0 = cb * chunk;
    const int j1 = (cb == nchunk - 1) ? K : j0 + chunk;
    const float* wr = w + (size_t)r * K;
    float s = 0.f;
    for (int j = j0 + (int)threadIdx.x * 4; j + 3 < j1; j += blockDim.x * 4) {
        float4 hv = *reinterpret_cast<const float4*>(h + j);
        float4 wv = *reinterpret_cast<const float4*>(wr + j);
        s += hv.x * wv.x + hv.y * wv.y + hv.z * wv.z + hv.w * wv.w;
    }
    __shared__ float red[256];
    red[threadIdx.x] = s;
    __syncthreads();
    for (int off = 128; off > 0; off >>= 1) {
        if ((int)threadIdx.x < off) red[threadIdx.x] += red[threadIdx.x + off];
        __syncthreads();
    }
    if (threadIdx.x == 0) partial[r * gridDim.x + cb] = red[0];
}

__global__ void fc_final_kernel(const float* __restrict__ partial,
                                const float* __restrict__ b, int nchunk,
                                float* __restrict__ out) {
    int r = threadIdx.x;
    if (r < 50) {
        float s = b[r];
        for (int i = 0; i < nchunk; ++i) s += partial[r * nchunk + i];
        out[r] = s;
    }
}

// ---------------------------------------------------------------------------
extern "C" void kernel_launch(void* const* d_in, const int* in_sizes, int n_in,
                              void* d_out, int out_size, void* d_ws, size_t ws_size,
                              hipStream_t stream) {
    const float* x    = (const float*)d_in[0];
    const float* c1w  = (const float*)d_in[1];
    const float* c1b  = (const float*)d_in[2];
    const float* bn1g = (const float*)d_in[3];
    const float* bn1b = (const float*)d_in[4];
    const float* a1qw = (const float*)d_in[5];
    const float* a1qb = (const float*)d_in[6];
    const float* a1kw = (const float*)d_in[7];
    const float* a1kb = (const float*)d_in[8];
    const float* a1vw = (const float*)d_in[9];
    const float* a1vb = (const float*)d_in[10];
    const float* a1g  = (const float*)d_in[11];
    const float* c2w  = (const float*)d_in[12];
    const float* c2b  = (const float*)d_in[13];
    const float* bn2g = (const float*)d_in[14];
    const float* bn2b = (const float*)d_in[15];
    const float* a2qw = (const float*)d_in[16];
    const float* a2qb = (const float*)d_in[17];
    const float* a2kw = (const float*)d_in[18];
    const float* a2kb = (const float*)d_in[19];
    const float* a2vw = (const float*)d_in[20];
    const float* a2vb = (const float*)d_in[21];
    const float* a2g  = (const float*)d_in[22];
    const float* fcw  = (const float*)d_in[23];
    const float* fcb  = (const float*)d_in[24];
    float* out = (float*)d_out;

    const int N1 = 127 * 127;          // 16129
    const int N2 = 62 * 62;            // 3844
    const int NP1 = (N1 + 7) & ~7;     // 16136
    const int NP2 = (N2 + 7) & ~7;     // 3848
    const int NS1 = 8, NS2 = 16;

    char* base = (char*)d_ws;
    size_t off = 0;
    auto alloc = [&](size_t bytes) {
        void* p = base + off;
        off += (bytes + 63) & ~(size_t)63;
        return p;
    };
    float* h1   = (float*)alloc(sizeof(float) * 32 * 254 * 254);
    float* bnP  = (float*)alloc(sizeof(float) * 64 * 8 * 2);
    float* bnA  = (float*)alloc(sizeof(float) * 64);
    float* p1   = (float*)alloc(sizeof(float) * 32 * N1);
    float* q1   = (float*)alloc(sizeof(float) * 4 * NP1);
    float* k1   = (float*)alloc(sizeof(float) * 4 * NP1);
    unsigned short* v1 = (unsigned short*)alloc(sizeof(short) * 32 * NP1);
    float* l1   = (float*)alloc(sizeof(float) * NS1 * N1);
    float* a1p  = (float*)alloc(sizeof(float) * (size_t)NS1 * N1 * 32);
    float* ao1  = (float*)alloc(sizeof(float) * 32 * N1);
    float* h2   = (float*)alloc(sizeof(float) * 64 * 125 * 125);
    float* bnB  = (float*)alloc(sizeof(float) * 128);
    float* p2   = (float*)alloc(sizeof(float) * 64 * N2);
    float* q2   = (float*)alloc(sizeof(float) * 8 * NP2);
    float* k2   = (float*)alloc(sizeof(float) * 8 * NP2);
    unsigned short* v2 = (unsigned short*)alloc(sizeof(short) * 64 * NP2);
    float* l2   = (float*)alloc(sizeof(float) * NS2 * N2);
    float* a2p  = (float*)alloc(sizeof(float) * (size_t)NS2 * N2 * 64);
    float* ao2  = (float*)alloc(sizeof(float) * 64 * N2);
    float* fcp  = (float*)alloc(sizeof(float) * 512);

    // ---- stage 1: conv1 [3,256,256] -> [32,254,254]
    {
        size_t smem = (3 * 324 + 3 * 9) * sizeof(float);
        conv3x3_kernel<<<dim3(16, 16, 32), dim3(16, 16), smem, stream>>>(
            x, 3, 256, 256, c1w, c1b, h1, 254, 254);
    }
    bn_part_kernel<<<dim3(32, 8), 256, 0, stream>>>(h1, 254 * 254, bnP);
    bn_final_kernel<<<32, 64, 0, stream>>>(bnP, 8, 254 * 254, bn1g, bn1b, bnA);
    bn_pool_kernel<<<(32 * N1 + 255) / 256, 256, 0, stream>>>(
        h1, bnA, 254, 254, 127, 127, 32, p1);

    // ---- attention 1 (C=32, Cqk=4, N=16129)
    qkv_proj_kernel<<<dim3((N1 + 255) / 256, 5), 256, 0, stream>>>(
        p1, N1, NP1, 32, 4, a1qw, a1qb, a1kw, a1kb, a1vw, a1vb, q1, k1, v1);
    {
        int chunk = (N1 + NS1 - 1) / NS1;   // 2017
        flash_mfma_kernel<4, 32><<<dim3((N1 + 63) / 64, NS1), 256, 0, stream>>>(
            q1, k1, v1, N1, NP1, chunk, l1, a1p);
    }
    combine_kernel<<<(32 * N1 + 255) / 256, 256, 0, stream>>>(
        a1p, l1, NS1, N1, 32, a1g, p1, ao1);

    // ---- stage 2: conv2 [32,127,127] -> [64,125,125]
    {
        size_t smem = (32 * 324 + 32 * 9) * sizeof(float);
        conv3x3_kernel<<<dim3(8, 8, 64), dim3(16, 16), smem, stream>>>(
            ao1, 32, 127, 127, c2w, c2b, h2, 125, 125);
    }
    bn_part_kernel<<<dim3(64, 8), 256, 0, stream>>>(h2, 125 * 125, bnP);
    bn_final_kernel<<<64, 64, 0, stream>>>(bnP, 8, 125 * 125, bn2g, bn2b, bnB);
    bn_pool_kernel<<<(64 * N2 + 255) / 256, 256, 0, stream>>>(
        h2, bnB, 125, 125, 62, 62, 64, p2);

    // ---- attention 2 (C=64, Cqk=8, N=3844)
    qkv_proj_kernel<<<dim3((N2 + 255) / 256, 10), 256, 0, stream>>>(
        p2, N2, NP2, 64, 8, a2qw, a2qb, a2kw, a2kb, a2vw, a2vb, q2, k2, v2);
    {
        int chunk = (N2 + NS2 - 1) / NS2;   // 241
        flash_mfma_kernel<8, 64><<<dim3((N2 + 63) / 64, NS2), 256, 0, stream>>>(
            q2, k2, v2, N2, NP2, chunk, l2, a2p);
    }
    combine_kernel<<<(64 * N2 + 255) / 256, 256, 0, stream>>>(
        a2p, l2, NS2, N2, 64, a2g, p2, ao2);

    // ---- FC [246016] -> [50]
    fc_partial_kernel<<<dim3(8, 50), 256, 0, stream>>>(ao2, fcw, 64 * N2, 8, fcp);
    fc_final_kernel<<<1, 64, 0, stream>>>(fcp, fcb, 8, out);
}